// Round 14
// baseline (126.013 us; speedup 1.0000x reference)
//
#include <hip/hip_runtime.h>
#include <math.h>

#define SEQ   1024
#define DQ    256
#define DVD   512
#define NHH   16          // B*NH
#define EPSF  1e-6f
#define INV_SQRT_D 0.0625f   // 1/sqrt(256)

typedef __attribute__((ext_vector_type(8)))  short short8v;
typedef __attribute__((ext_vector_type(16))) float f32x16;

// ---- workspace layout (float offsets) ----
#define WS_FG    0                        // [16][1024]
#define WS_IG    (NHH*SEQ)                // [16][1024]
#define WS_ELIM  (2*NHH*SEQ)              // [16][1024]  exp(-m_t)
#define WS_AT    (3*NHH*SEQ)              // [16][1024]  a_t = F_t - m_t
#define WS_CS    (4*NHH*SEQ)              // [16][1024]  c_s = i_s - F_s
#define WS_AC    (5*NHH*SEQ)              // [16][16]
#define WS_BVEC  (WS_AC + NHH*16)         // [16][16][256]
#define WS_SMALL_FLOATS (WS_BVEC + NHH*16*DQ)

#define KBF_OFF  ((size_t)WS_SMALL_FLOATS * 4)             // bytes (16-aligned)
#define VTB_OFF  (KBF_OFF + (size_t)NHH*SEQ*DQ*2)          // vt_bf [h][v][t]
#define KUT_OFF  (VTB_OFF + (size_t)NHH*DVD*SEQ*2)

__device__ __forceinline__ unsigned short f2bf(float f) {
  unsigned int u = __float_as_uint(f);
  return (unsigned short)((u + 0x7fffu + ((u >> 16) & 1u)) >> 16);
}

__device__ __forceinline__ void gl_lds16(const void* g, void* l) {
  __builtin_amdgcn_global_load_lds(
      (const __attribute__((address_space(1))) unsigned int*)g,
      (__attribute__((address_space(3))) unsigned int*)l, 16, 0, 0);
}

// ============================================================
// Role-fused prep kernel with INLINE gate scan (verbatim from R11/R13).
//  blocks [0,256): (head,chunk64) — inline per-head scan; c==0 writes ws;
//    then k_bf cast, bvec, kut.
//  blocks [256,768): (head, 32-row t-group) — v -> vt_bf [h][v][t].
// ============================================================
__global__ __launch_bounds__(256) void prep_kernel(
    const float* __restrict__ kin, const float* __restrict__ vin,
    const float* __restrict__ ipre, const float* __restrict__ fpre,
    float* __restrict__ ws,
    unsigned short* __restrict__ k_bf, unsigned short* __restrict__ vt_bf,
    unsigned short* __restrict__ kut, float* __restrict__ m_out) {
  __shared__ float lk[64][257];      // role-a k tile; role-b reuses as [32][33]
  __shared__ float swsum[4], swmax[4];
  __shared__ float bndF[16], bndM[16], fin2[2];
  __shared__ float cfg[64], cig[64], cut[64];

  const int b = blockIdx.x;
  if (b < 256) {
    const int hh = b >> 4, c = b & 15;
    const int d = threadIdx.x;
    const int lane = d & 63, wid = d >> 6;   // 4 waves
    const int tbase = hh*SEQ + c*64;
    const size_t base = (size_t)tbase * DQ;

    #pragma unroll 4
    for (int tt = 0; tt < 64; ++tt) {
      const float val = kin[base + (size_t)tt*DQ + d];
      lk[tt][d] = val;
      k_bf[base + (size_t)tt*DQ + d] = f2bf(val);
    }

    const float4 f4 = *(const float4*)(fpre + hh*SEQ + 4*d);
    const float4 i4 = *(const float4*)(ipre + hh*SEQ + 4*d);
    float fv[4] = {f4.x, f4.y, f4.z, f4.w};
    float iv[4] = {i4.x, i4.y, i4.z, i4.w};
    float fl[4], F[4];
    float s = 0.f;
    #pragma unroll
    for (int j = 0; j < 4; ++j) {
      fl[j] = fminf(fv[j], 0.f) - log1pf(expf(-fabsf(fv[j])));
      s += fl[j]; F[j] = s;
    }
    float wsc = s;
    #pragma unroll
    for (int off = 1; off < 64; off <<= 1) {
      float o = __shfl_up(wsc, off, 64);
      if (lane >= off) wsc += o;
    }
    if (lane == 63) swsum[wid] = wsc;
    __syncthreads();
    float woff = 0.f;
    #pragma unroll
    for (int i = 0; i < 4; ++i) { float t = swsum[i]; if (i < wid) woff += t; }
    const float Fexc = woff + (wsc - s);
    #pragma unroll
    for (int j = 0; j < 4; ++j) F[j] += Fexc;

    float zser[4];
    float zs = -INFINITY;
    #pragma unroll
    for (int j = 0; j < 4; ++j) {
      zs = fmaxf(zs, iv[j] - F[j]); zser[j] = zs;
    }
    float zmI = zs;
    #pragma unroll
    for (int off = 1; off < 64; off <<= 1) {
      float o = __shfl_up(zmI, off, 64);
      if (lane >= off) zmI = fmaxf(zmI, o);
    }
    if (lane == 63) swmax[wid] = zmI;
    float zexcl = __shfl_up(zmI, 1, 64);
    if (lane == 0) zexcl = -INFINITY;
    __syncthreads();
    float zoffW = -INFINITY;
    #pragma unroll
    for (int i = 0; i < 4; ++i) { float t = swmax[i]; if (i < wid) zoffW = fmaxf(zoffW, t); }
    const float zPexc = fmaxf(zoffW, zexcl);

    float mprev = Fexc + fmaxf(zPexc, 0.f);
    float m_[4], fg_[4], ig_[4];
    #pragma unroll
    for (int j = 0; j < 4; ++j) {
      const float zP = fmaxf(zPexc, zser[j]);
      m_[j] = F[j] + fmaxf(zP, 0.f);
      fg_[j] = expf(fl[j] + mprev - m_[j]);
      ig_[j] = expf(iv[j] - m_[j]);
      mprev = m_[j];
    }

    if ((d & 15) == 15) { bndF[d >> 4] = F[3]; bndM[d >> 4] = m_[3]; }
    if (d == 255)       { fin2[0] = F[3]; fin2[1] = m_[3]; }
    const int q0 = d - 16*c;
    if (q0 >= 0 && q0 < 16) {
      #pragma unroll
      for (int j = 0; j < 4; ++j) { cfg[q0*4 + j] = fg_[j]; cig[q0*4 + j] = ig_[j]; }
    }
    if (c == 0) {
      float4 o;
      o.x=fg_[0]; o.y=fg_[1]; o.z=fg_[2]; o.w=fg_[3];
      *(float4*)(ws + WS_FG + hh*SEQ + 4*d) = o;
      o.x=ig_[0]; o.y=ig_[1]; o.z=ig_[2]; o.w=ig_[3];
      *(float4*)(ws + WS_IG + hh*SEQ + 4*d) = o;
      o.x=expf(-m_[0]); o.y=expf(-m_[1]); o.z=expf(-m_[2]); o.w=expf(-m_[3]);
      *(float4*)(ws + WS_ELIM + hh*SEQ + 4*d) = o;
      o.x=F[0]-m_[0]; o.y=F[1]-m_[1]; o.z=F[2]-m_[2]; o.w=F[3]-m_[3];
      *(float4*)(ws + WS_AT + hh*SEQ + 4*d) = o;
      o.x=iv[0]-F[0]; o.y=iv[1]-F[1]; o.z=iv[2]-F[2]; o.w=iv[3]-F[3];
      *(float4*)(ws + WS_CS + hh*SEQ + 4*d) = o;
      if (d == 255) m_out[hh] = m_[3];
    }
    __syncthreads();
    if (c == 0 && d < 16) {
      const float Fp = d ? bndF[d-1] : 0.f;
      const float mp = d ? bndM[d-1] : 0.f;
      ws[WS_AC + hh*16 + d] = expf((bndF[d] - Fp) + (mp - bndM[d]));
    }
    if (q0 >= 0 && q0 < 16) {
      const float Fe = fin2[0], me = fin2[1];
      #pragma unroll
      for (int j = 0; j < 4; ++j)
        cut[q0*4 + j] = expf(Fe - F[j] + iv[j] - me);
    }
    __syncthreads();

    float nb = 0.f;
    #pragma unroll 8
    for (int tt = 0; tt < 64; ++tt) nb = cfg[tt]*nb + cig[tt]*lk[tt][d];
    ws[WS_BVEC + (hh*16 + c)*DQ + d] = nb;
    #pragma unroll
    for (int g = 0; g < 8; ++g) {
      short8v pk;
      #pragma unroll
      for (int j = 0; j < 8; ++j) {
        const int tt = g*8 + j;
        pk[j] = (short)f2bf(cut[tt] * lk[tt][d]);
      }
      *(short8v*)(kut + ((size_t)(hh*DQ + d))*SEQ + c*64 + g*8) = pk;
    }
  } else {
    const int b2 = b - 256;            // 0..511
    const int hh = b2 >> 5, tg = b2 & 31;
    const int tx = threadIdx.x & 31, ty = threadIdx.x >> 5;
    float (*tile)[33] = (float(*)[33])lk;
    for (int vt = 0; vt < 16; ++vt) {
      #pragma unroll
      for (int i = 0; i < 4; ++i)
        tile[ty + 8*i][tx] =
            vin[((size_t)(hh*SEQ + tg*32 + ty + 8*i))*DVD + vt*32 + tx];
      __syncthreads();
      #pragma unroll
      for (int i = 0; i < 4; ++i)
        vt_bf[((size_t)(hh*DVD + vt*32 + ty + 8*i))*SEQ + tg*32 + tx] =
            f2bf(tile[tx][ty + 8*i]);
      __syncthreads();
    }
  }
}

// ============================================================
// Fused main kernel.
//  blocks [0,512): attn — VERBATIM R10/R13 chunk loop; prologue computes
//    this q-tile's exact fp32 denominator inline (hden chunk == q-tile),
//    using Klds as fp32 scratch before stage(0); qfrag cast from q fp32
//    (bit-identical to the old q_bf values). Block (qi==15,vh==0) writes n_out.
//  blocks [512,768): cgemm — verbatim body, tid<256-guarded, uniform barriers,
//    Alds/Blds carved from Klds/Vtlds. Fills attn's LPT tail.
// ============================================================
__global__ __launch_bounds__(512, 2) void fused_kernel(
    const float* __restrict__ qin, const float* __restrict__ kin,
    const unsigned short* __restrict__ k_bf,
    const unsigned short* __restrict__ vt_bf,
    const unsigned short* __restrict__ kut,
    const float* __restrict__ ws,
    float* __restrict__ h_out, float* __restrict__ C_out,
    float* __restrict__ n_out) {
  __shared__ unsigned short Klds[128*256];   // 64 KB (also fp32 pbuf scratch)
  __shared__ unsigned short Vtlds[256*128];  // 64 KB (also cgemm Blds)
  __shared__ unsigned short Plds[64*128];    // 16 KB
  __shared__ float c_lds[128];
  __shared__ float spart[64][4];
  __shared__ float hd_lds[64];

  const int b = blockIdx.x;
  const int tid = threadIdx.x;

  if (b < 512) {
    // ================= attn path =================
    const int phase = b >> 8;
    const int idx = b & 255;
    const int hh = idx & 15;
    const int vh = (idx >> 4) & 1;
    const int qq = idx >> 5;
    const int qi = phase ? (15 - qq) : qq;      // LPT: shorts first, longs desc
    const int nch = (qi >> 1) + 1;

    const int w = tid >> 6, lane = tid & 63, l31 = lane & 31, hl = lane >> 5;
    const int tsub = w >> 2;        // 0..1: 32-row t-group
    const int sblk = w & 3;         // S-phase s-block
    const int vsub = w & 3;         // PV v-slice (64)

    const float* a_g  = ws + WS_AT;
    const float* c_g  = ws + WS_CS;

    const int tbase = hh*SEQ + qi*64;

    // ---- prologue: exact fp32 denominator for this 64-row chunk ----
    {
      float* pbuf = (float*)Klds;            // [64][256] scratch
      if (tid < 256) {
        const int d = tid;
        float n = 0.f;
        for (int j = 0; j < qi; ++j)
          n = ws[WS_AC + hh*16 + j]*n + ws[WS_BVEC + (hh*16 + j)*DQ + d];
        if (qi == 15 && vh == 0) {
          const float nf = ws[WS_AC + hh*16 + 15]*n +
                           ws[WS_BVEC + (hh*16 + 15)*DQ + d];
          n_out[hh*DQ + d] = nf;
        }
        const size_t base = (size_t)tbase * DQ;
        #pragma unroll 4
        for (int tt = 0; tt < 64; ++tt) {
          const float fg = ws[WS_FG + tbase + tt];
          const float ig = ws[WS_IG + tbase + tt];
          n = fg*n + ig*kin[base + (size_t)tt*DQ + d];
          pbuf[tt*256 + d] = n * qin[base + (size_t)tt*DQ + d];
        }
      }
      __syncthreads();
      if (tid < 256) {
        const int d = tid;
        const int tt = d >> 2, qd = d & 3;
        float s = 0.f;
        #pragma unroll 8
        for (int j = 0; j < 64; ++j)
          s += pbuf[tt*256 + qd*64 + ((j + d) & 63)];
        spart[tt][qd] = s;
      }
      __syncthreads();
      if (tid < 64) {
        const float tot = (spart[tid][0] + spart[tid][1]) +
                          (spart[tid][2] + spart[tid][3]);
        const float qn = tot * INV_SQRT_D;
        hd_lds[tid] = fmaxf(fabsf(qn), ws[WS_ELIM + tbase + tid]) + EPSF;
      }
      __syncthreads();
    }

    const int tq = qi*64 + tsub*32 + l31;      // lane's t-column
    const float a_t = a_g[hh*SEQ + tq];

    // qfrag from q fp32 (bit-identical to old q_bf: f2bf(qv/16))
    short8v qfrag[16];
    {
      const float* qrow = qin + (size_t)(hh*SEQ + tq)*DQ;
      #pragma unroll
      for (int d2 = 0; d2 < 16; ++d2) {
        const float4 a = *(const float4*)(qrow + d2*16 + hl*8);
        const float4 bq = *(const float4*)(qrow + d2*16 + hl*8 + 4);
        short8v f;
        f[0]=(short)f2bf(a.x*INV_SQRT_D);  f[1]=(short)f2bf(a.y*INV_SQRT_D);
        f[2]=(short)f2bf(a.z*INV_SQRT_D);  f[3]=(short)f2bf(a.w*INV_SQRT_D);
        f[4]=(short)f2bf(bq.x*INV_SQRT_D); f[5]=(short)f2bf(bq.y*INV_SQRT_D);
        f[6]=(short)f2bf(bq.z*INV_SQRT_D); f[7]=(short)f2bf(bq.w*INV_SQRT_D);
        qfrag[d2] = f;
      }
    }

    f32x16 acc0 = {}, acc1 = {};

    auto stage = [&](int c) {
      const int s0 = c*128;
      #pragma unroll
      for (int p = 0; p < 8; ++p) {
        int u = p*512 + tid;
        int row = u >> 5, slot = u & 31;
        const unsigned short* src = k_bf +
            ((size_t)(hh*SEQ + s0 + row))*DQ + ((slot ^ (row & 31))*8);
        gl_lds16(src, (char*)Klds + (p*8 + w)*1024);
      }
      #pragma unroll
      for (int p = 0; p < 8; ++p) {
        int u = p*512 + tid;
        int row = u >> 4, slot = u & 15;
        const unsigned short* src = vt_bf +
            ((size_t)(hh*DVD + vh*256 + row))*SEQ + s0 + ((slot ^ (row & 15))*8);
        gl_lds16(src, (char*)Vtlds + (p*8 + w)*1024);
      }
      if (tid < 128) c_lds[tid] = c_g[hh*SEQ + s0 + tid];
    };

    stage(0);
    __syncthreads();

    for (int c = 0; c < nch; ++c) {
      const int s0 = c*128;
      // ---- S-phase: S^T[s][t] for subtile (sblk, tsub) ----
      f32x16 sacc = {};
      const int srow = sblk*32 + l31;
      #pragma unroll
      for (int d = 0; d < 16; ++d) {
        short8v af = *(const short8v*)&Klds[srow*256 + (((d*2 + hl) ^ (srow & 31))*8)];
        sacc = __builtin_amdgcn_mfma_f32_32x32x16_bf16(af, qfrag[d], sacc, 0, 0, 0);
      }
      // weight, mask, pack bf16, write to Plds (swizzled)
      const int prow = tsub*32 + l31;
      #pragma unroll
      for (int i = 0; i < 8; ++i) {
        const int r0 = 2*i;
        const int sl = sblk*32 + (r0 & 3) + 8*(r0 >> 2) + 4*hl;
        const int sg = s0 + sl;
        const float c0 = c_lds[sl];
        const float c1 = c_lds[sl + 1];
        const float p0 = (sg     <= tq) ? __expf(a_t + c0) * sacc[r0]     : 0.f;
        const float p1 = (sg + 1 <= tq) ? __expf(a_t + c1) * sacc[r0 + 1] : 0.f;
        unsigned int pk;
        asm volatile("v_cvt_pk_bf16_f32 %0, %1, %2" : "=v"(pk) : "v"(p0), "v"(p1));
        const int byte = sl*2;
        const int slot = byte >> 4, rem = byte & 15;
        *(unsigned int*)((char*)Plds + prow*256 + ((slot ^ (prow & 15))<<4) + rem) = pk;
      }
      __syncthreads();

      // ---- PV phase: acc[t][v] += P[t][s] * V[s][v] ----
      #pragma unroll
      for (int ss = 0; ss < 8; ++ss) {
        const int arow = tsub*32 + l31;
        short8v pa = *(const short8v*)&Plds[arow*128 + (((ss*2 + hl) ^ (arow & 15))*8)];
        const int vr0 = vsub*64 + l31;
        const int slotB = (ss*2 + hl) ^ (l31 & 15);
        short8v vb0 = *(const short8v*)&Vtlds[vr0*128 + slotB*8];
        short8v vb1 = *(const short8v*)&Vtlds[(vr0 + 32)*128 + slotB*8];
        acc0 = __builtin_amdgcn_mfma_f32_32x32x16_bf16(pa, vb0, acc0, 0, 0, 0);
        acc1 = __builtin_amdgcn_mfma_f32_32x32x16_bf16(pa, vb1, acc1, 0, 0, 0);
      }
      __syncthreads();
      if (c + 1 < nch) { stage(c + 1); __syncthreads(); }
    }

    // ---- epilogue: local exact denominator, write h ----
    #pragma unroll
    for (int r = 0; r < 16; ++r) {
      const int tl = tsub*32 + (r & 3) + 8*(r >> 2) + 4*hl;
      const int tg = qi*64 + tl;
      const float inv = 1.0f / hd_lds[tl];
      const size_t ob = ((size_t)(hh*SEQ + tg))*DVD + vh*256 + vsub*64 + l31;
      h_out[ob]      = acc0[r] * inv;
      h_out[ob + 32] = acc1[r] * inv;
    }
  } else {
    // ================= cgemm path (verbatim body, tid<256-guarded) =========
    unsigned short* Alds = (unsigned short*)Klds;   // 16 KB used
    unsigned short* Blds = (unsigned short*)Vtlds;  //  8 KB used
    const int b2 = b - 512;       // 16h x 2mt x 8nt
    const int hh = b2 >> 4;
    const int mt = (b2 >> 3) & 1;
    const int nt = b2 & 7;
    const int w = tid >> 6, lane = tid & 63, l31 = lane & 31, hl = lane >> 5;
    const int mr = w >> 1;
    const int nc = w & 1;

    f32x16 acc0 = {}, acc1 = {};
    for (int c = 0; c < 16; ++c) {
      const int t0 = c*64;
      if (tid < 256) {
        #pragma unroll
        for (int p = 0; p < 4; ++p) {
          int u = p*256 + tid; int row = u >> 3, slot = u & 7;
          const unsigned short* src = kut +
              ((size_t)(hh*DQ + mt*128 + row))*SEQ + t0 + ((slot ^ (row & 7))*8);
          gl_lds16(src, (char*)Alds + (p*4 + w)*1024);
        }
        #pragma unroll
        for (int p = 0; p < 2; ++p) {
          int u = p*256 + tid; int row = u >> 3, slot = u & 7;
          const unsigned short* src = vt_bf +
              ((size_t)(hh*DVD + nt*64 + row))*SEQ + t0 + ((slot ^ (row & 7))*8);
          gl_lds16(src, (char*)Blds + (p*4 + w)*1024);
        }
      }
      __syncthreads();
      if (tid < 256) {
        #pragma unroll
        for (int ks = 0; ks < 4; ++ks) {
          const int br = nc*32 + l31;
          short8v bf_ = *(const short8v*)&Blds[br*64 + (((ks*2 + hl) ^ (br & 7))*8)];
          const int ar0 = mr*64 + l31, ar1 = ar0 + 32;
          short8v a0 = *(const short8v*)&Alds[ar0*64 + (((ks*2 + hl) ^ (ar0 & 7))*8)];
          short8v a1 = *(const short8v*)&Alds[ar1*64 + (((ks*2 + hl) ^ (ar1 & 7))*8)];
          acc0 = __builtin_amdgcn_mfma_f32_32x32x16_bf16(a0, bf_, acc0, 0, 0, 0);
          acc1 = __builtin_amdgcn_mfma_f32_32x32x16_bf16(a1, bf_, acc1, 0, 0, 0);
        }
      }
      __syncthreads();
    }
    if (tid < 256) {
      #pragma unroll
      for (int r = 0; r < 16; ++r) {
        const int dl = (r & 3) + 8*(r >> 2) + 4*hl;
        const int d0 = mt*128 + mr*64 + dl;
        const size_t ob = ((size_t)(hh*DQ + d0))*DVD + nt*64 + nc*32 + l31;
        C_out[ob]            = acc0[r];
        C_out[ob + 32*DVD]   = acc1[r];
      }
    }
  }
}

// ============================================================
extern "C" void kernel_launch(void* const* d_in, const int* in_sizes, int n_in,
                              void* d_out, int out_size, void* d_ws, size_t ws_size,
                              hipStream_t stream) {
  const float* q  = (const float*)d_in[0];
  const float* k  = (const float*)d_in[1];
  const float* v  = (const float*)d_in[2];
  const float* ip = (const float*)d_in[3];
  const float* fp = (const float*)d_in[4];

  float* h_out = (float*)d_out;                       // [16][1024][512]
  float* C_out = h_out + (size_t)NHH*SEQ*DVD;         // [16][256][512]
  float* n_out = C_out + (size_t)NHH*DQ*DVD;          // [16][256]
  float* m_out = n_out + NHH*DQ;                      // [16]
  float* ws    = (float*)d_ws;

  unsigned short* k_bf  = (unsigned short*)((char*)d_ws + KBF_OFF);
  unsigned short* vt_bf = (unsigned short*)((char*)d_ws + VTB_OFF);
  unsigned short* kut   = (unsigned short*)((char*)d_ws + KUT_OFF);

  prep_kernel<<<768, 256, 0, stream>>>(k, v, ip, fp, ws, k_bf, vt_bf, kut, m_out);
  fused_kernel<<<768, 512, 0, stream>>>(q, k, k_bf, vt_bf, kut, ws,
                                        h_out, C_out, n_out);
}

// Round 15
// 88.442 us; speedup vs baseline: 1.4248x; 1.4248x over previous
//
#include <hip/hip_runtime.h>
#include <math.h>

#define SEQ   1024
#define DQ    256
#define DVD   512
#define NHH   16          // B*NH
#define EPSF  1e-6f
#define INV_SQRT_D 0.0625f   // 1/sqrt(256)

typedef __attribute__((ext_vector_type(8)))  short short8v;
typedef __attribute__((ext_vector_type(16))) float f32x16;

// ---- workspace layout (float offsets) ----
#define WS_FG    0                        // [16][1024]
#define WS_IG    (NHH*SEQ)                // [16][1024]
#define WS_ELIM  (2*NHH*SEQ)              // [16][1024]  exp(-m_t)
#define WS_HDEN  (3*NHH*SEQ)              // [16][1024]
#define WS_AT    (4*NHH*SEQ)              // [16][1024]  a_t = F_t - m_t
#define WS_CS    (5*NHH*SEQ)              // [16][1024]  c_s = i_s - F_s
#define WS_AC    (6*NHH*SEQ)              // [16][16]
#define WS_BVEC  (WS_AC + NHH*16)         // [16][16][256]
#define WS_SMALL_FLOATS (WS_BVEC + NHH*16*DQ)

#define QBF_OFF  ((size_t)WS_SMALL_FLOATS * 4)             // bytes (16-aligned)
#define KBF_OFF  (QBF_OFF + (size_t)NHH*SEQ*DQ*2)
#define VTB_OFF  (KBF_OFF + (size_t)NHH*SEQ*DQ*2)          // vt_bf [h][v][t]
#define KUT_OFF  (VTB_OFF + (size_t)NHH*DVD*SEQ*2)

__device__ __forceinline__ unsigned short f2bf(float f) {
  unsigned int u = __float_as_uint(f);
  return (unsigned short)((u + 0x7fffu + ((u >> 16) & 1u)) >> 16);
}

__device__ __forceinline__ void gl_lds16(const void* g, void* l) {
  __builtin_amdgcn_global_load_lds(
      (const __attribute__((address_space(1))) unsigned int*)g,
      (__attribute__((address_space(3))) unsigned int*)l, 16, 0, 0);
}

// ============================================================
// Role-fused prep kernel with INLINE gate scan (verbatim from R11/R13).
//  blocks [0,256): (head,chunk64) — inline per-head scan; c==0 writes ws;
//    then k_bf cast, bvec, kut.
//  blocks [256,768): (head, 32-row t-group) — v -> vt_bf [h][v][t].
// ============================================================
__global__ __launch_bounds__(256) void prep_kernel(
    const float* __restrict__ kin, const float* __restrict__ vin,
    const float* __restrict__ ipre, const float* __restrict__ fpre,
    float* __restrict__ ws,
    unsigned short* __restrict__ k_bf, unsigned short* __restrict__ vt_bf,
    unsigned short* __restrict__ kut, float* __restrict__ m_out) {
  __shared__ float lk[64][257];      // role-a k tile; role-b reuses as [32][33]
  __shared__ float swsum[4], swmax[4];
  __shared__ float bndF[16], bndM[16], fin2[2];
  __shared__ float cfg[64], cig[64], cut[64];

  const int b = blockIdx.x;
  if (b < 256) {
    const int hh = b >> 4, c = b & 15;
    const int d = threadIdx.x;
    const int lane = d & 63, wid = d >> 6;   // 4 waves
    const int tbase = hh*SEQ + c*64;
    const size_t base = (size_t)tbase * DQ;

    #pragma unroll 4
    for (int tt = 0; tt < 64; ++tt) {
      const float val = kin[base + (size_t)tt*DQ + d];
      lk[tt][d] = val;
      k_bf[base + (size_t)tt*DQ + d] = f2bf(val);
    }

    const float4 f4 = *(const float4*)(fpre + hh*SEQ + 4*d);
    const float4 i4 = *(const float4*)(ipre + hh*SEQ + 4*d);
    float fv[4] = {f4.x, f4.y, f4.z, f4.w};
    float iv[4] = {i4.x, i4.y, i4.z, i4.w};
    float fl[4], F[4];
    float s = 0.f;
    #pragma unroll
    for (int j = 0; j < 4; ++j) {
      fl[j] = fminf(fv[j], 0.f) - log1pf(expf(-fabsf(fv[j])));
      s += fl[j]; F[j] = s;
    }
    float wsc = s;
    #pragma unroll
    for (int off = 1; off < 64; off <<= 1) {
      float o = __shfl_up(wsc, off, 64);
      if (lane >= off) wsc += o;
    }
    if (lane == 63) swsum[wid] = wsc;
    __syncthreads();
    float woff = 0.f;
    #pragma unroll
    for (int i = 0; i < 4; ++i) { float t = swsum[i]; if (i < wid) woff += t; }
    const float Fexc = woff + (wsc - s);
    #pragma unroll
    for (int j = 0; j < 4; ++j) F[j] += Fexc;

    float zser[4];
    float zs = -INFINITY;
    #pragma unroll
    for (int j = 0; j < 4; ++j) {
      zs = fmaxf(zs, iv[j] - F[j]); zser[j] = zs;
    }
    float zmI = zs;
    #pragma unroll
    for (int off = 1; off < 64; off <<= 1) {
      float o = __shfl_up(zmI, off, 64);
      if (lane >= off) zmI = fmaxf(zmI, o);
    }
    if (lane == 63) swmax[wid] = zmI;
    float zexcl = __shfl_up(zmI, 1, 64);
    if (lane == 0) zexcl = -INFINITY;
    __syncthreads();
    float zoffW = -INFINITY;
    #pragma unroll
    for (int i = 0; i < 4; ++i) { float t = swmax[i]; if (i < wid) zoffW = fmaxf(zoffW, t); }
    const float zPexc = fmaxf(zoffW, zexcl);

    float mprev = Fexc + fmaxf(zPexc, 0.f);
    float m_[4], fg_[4], ig_[4];
    #pragma unroll
    for (int j = 0; j < 4; ++j) {
      const float zP = fmaxf(zPexc, zser[j]);
      m_[j] = F[j] + fmaxf(zP, 0.f);
      fg_[j] = expf(fl[j] + mprev - m_[j]);
      ig_[j] = expf(iv[j] - m_[j]);
      mprev = m_[j];
    }

    if ((d & 15) == 15) { bndF[d >> 4] = F[3]; bndM[d >> 4] = m_[3]; }
    if (d == 255)       { fin2[0] = F[3]; fin2[1] = m_[3]; }
    const int q0 = d - 16*c;
    if (q0 >= 0 && q0 < 16) {
      #pragma unroll
      for (int j = 0; j < 4; ++j) { cfg[q0*4 + j] = fg_[j]; cig[q0*4 + j] = ig_[j]; }
    }
    if (c == 0) {
      float4 o;
      o.x=fg_[0]; o.y=fg_[1]; o.z=fg_[2]; o.w=fg_[3];
      *(float4*)(ws + WS_FG + hh*SEQ + 4*d) = o;
      o.x=ig_[0]; o.y=ig_[1]; o.z=ig_[2]; o.w=ig_[3];
      *(float4*)(ws + WS_IG + hh*SEQ + 4*d) = o;
      o.x=expf(-m_[0]); o.y=expf(-m_[1]); o.z=expf(-m_[2]); o.w=expf(-m_[3]);
      *(float4*)(ws + WS_ELIM + hh*SEQ + 4*d) = o;
      o.x=F[0]-m_[0]; o.y=F[1]-m_[1]; o.z=F[2]-m_[2]; o.w=F[3]-m_[3];
      *(float4*)(ws + WS_AT + hh*SEQ + 4*d) = o;
      o.x=iv[0]-F[0]; o.y=iv[1]-F[1]; o.z=iv[2]-F[2]; o.w=iv[3]-F[3];
      *(float4*)(ws + WS_CS + hh*SEQ + 4*d) = o;
      if (d == 255) m_out[hh] = m_[3];
    }
    __syncthreads();
    if (c == 0 && d < 16) {
      const float Fp = d ? bndF[d-1] : 0.f;
      const float mp = d ? bndM[d-1] : 0.f;
      ws[WS_AC + hh*16 + d] = expf((bndF[d] - Fp) + (mp - bndM[d]));
    }
    if (q0 >= 0 && q0 < 16) {
      const float Fe = fin2[0], me = fin2[1];
      #pragma unroll
      for (int j = 0; j < 4; ++j)
        cut[q0*4 + j] = expf(Fe - F[j] + iv[j] - me);
    }
    __syncthreads();

    float nb = 0.f;
    #pragma unroll 8
    for (int tt = 0; tt < 64; ++tt) nb = cfg[tt]*nb + cig[tt]*lk[tt][d];
    ws[WS_BVEC + (hh*16 + c)*DQ + d] = nb;
    #pragma unroll
    for (int g = 0; g < 8; ++g) {
      short8v pk;
      #pragma unroll
      for (int j = 0; j < 8; ++j) {
        const int tt = g*8 + j;
        pk[j] = (short)f2bf(cut[tt] * lk[tt][d]);
      }
      *(short8v*)(kut + ((size_t)(hh*DQ + d))*SEQ + c*64 + g*8) = pk;
    }
  } else {
    const int b2 = b - 256;            // 0..511
    const int hh = b2 >> 5, tg = b2 & 31;
    const int tx = threadIdx.x & 31, ty = threadIdx.x >> 5;
    float (*tile)[33] = (float(*)[33])lk;
    for (int vt = 0; vt < 16; ++vt) {
      #pragma unroll
      for (int i = 0; i < 4; ++i)
        tile[ty + 8*i][tx] =
            vin[((size_t)(hh*SEQ + tg*32 + ty + 8*i))*DVD + vt*32 + tx];
      __syncthreads();
      #pragma unroll
      for (int i = 0; i < 4; ++i)
        vt_bf[((size_t)(hh*DVD + vt*32 + ty + 8*i))*SEQ + tg*32 + tx] =
            f2bf(tile[tx][ty + 8*i]);
      __syncthreads();
    }
  }
}

// ============================================================
// Merged aux kernel (verbatim R13): hden (blocks 0..255) + cgemm
// (blocks 256..511). Union'd LDS (66.5 KB -> 2 blocks/CU).
// ============================================================
__global__ __launch_bounds__(256) void aux_kernel(
    const float* __restrict__ kin, const float* __restrict__ qin,
    float* __restrict__ ws, unsigned short* __restrict__ q_bf,
    float* __restrict__ n_out,
    const unsigned short* __restrict__ kut,
    const unsigned short* __restrict__ vt,
    float* __restrict__ C_out) {
  __shared__ __align__(16) char smem[66560];
  const int b = blockIdx.x;

  if (b < 256) {
    // ---------------- hden role ----------------
    float (*pbuf)[DQ] = (float(*)[DQ])smem;            // 64 KB
    float (*spart)[4] = (float(*)[4])(smem + 65536);   //  1 KB
    const int hh = b >> 4;
    const int c  = b & 15;
    const int d  = threadIdx.x;

    float n = 0.f;
    for (int j = 0; j < c; ++j)
      n = ws[WS_AC + hh*16 + j]*n + ws[WS_BVEC + (hh*16 + j)*DQ + d];
    if (c == 15) {
      const float nf = ws[WS_AC + hh*16 + 15]*n +
                       ws[WS_BVEC + (hh*16 + 15)*DQ + d];
      n_out[hh*DQ + d] = nf;
    }

    const int tbase = hh*SEQ + c*64;
    const size_t base = (size_t)tbase * DQ;
    #pragma unroll 4
    for (int tt = 0; tt < 64; ++tt) {
      const float fg = ws[WS_FG + tbase + tt];
      const float ig = ws[WS_IG + tbase + tt];
      n = fg*n + ig*kin[base + (size_t)tt*DQ + d];
      const float qv = qin[base + (size_t)tt*DQ + d];
      q_bf[base + (size_t)tt*DQ + d] = f2bf(qv * INV_SQRT_D);
      pbuf[tt][d] = n * qv;
    }
    __syncthreads();

    {
      const int tt = d >> 2, qd = d & 3;
      float s = 0.f;
      #pragma unroll 8
      for (int j = 0; j < 64; ++j)
        s += pbuf[tt][qd*64 + ((j + d) & 63)];
      spart[tt][qd] = s;
    }
    __syncthreads();
    if (d < 64) {
      const float tot = (spart[d][0] + spart[d][1]) + (spart[d][2] + spart[d][3]);
      const float qn = tot * INV_SQRT_D;
      const float hd = fmaxf(fabsf(qn), ws[WS_ELIM + tbase + d]) + EPSF;
      ws[WS_HDEN + tbase + d] = hd;
    }
  } else {
    // ---------------- cgemm role ----------------
    unsigned short* Alds = (unsigned short*)smem;            // 16 KB [d][t]
    unsigned short* Blds = (unsigned short*)(smem + 16384);  //  8 KB [v][t]
    const int b2 = b - 256;       // 16h x 2mt x 8nt
    const int hh = b2 >> 4;
    const int mt = (b2 >> 3) & 1;
    const int nt = b2 & 7;
    const int tid = threadIdx.x;
    const int w = tid >> 6, lane = tid & 63, l31 = lane & 31, hl = lane >> 5;
    const int mr = w >> 1;
    const int nc = w & 1;

    f32x16 acc0 = {}, acc1 = {};
    for (int c = 0; c < 16; ++c) {
      const int t0 = c*64;
      #pragma unroll
      for (int p = 0; p < 4; ++p) {
        int u = p*256 + tid; int row = u >> 3, slot = u & 7;
        const unsigned short* src = kut +
            ((size_t)(hh*DQ + mt*128 + row))*SEQ + t0 + ((slot ^ (row & 7))*8);
        gl_lds16(src, (char*)Alds + (p*4 + w)*1024);
      }
      #pragma unroll
      for (int p = 0; p < 2; ++p) {
        int u = p*256 + tid; int row = u >> 3, slot = u & 7;
        const unsigned short* src = vt +
            ((size_t)(hh*DVD + nt*64 + row))*SEQ + t0 + ((slot ^ (row & 7))*8);
        gl_lds16(src, (char*)Blds + (p*4 + w)*1024);
      }
      __syncthreads();
      #pragma unroll
      for (int ks = 0; ks < 4; ++ks) {
        const int br = nc*32 + l31;
        short8v bf_ = *(const short8v*)&Blds[br*64 + (((ks*2 + hl) ^ (br & 7))*8)];
        const int ar0 = mr*64 + l31, ar1 = ar0 + 32;
        short8v a0 = *(const short8v*)&Alds[ar0*64 + (((ks*2 + hl) ^ (ar0 & 7))*8)];
        short8v a1 = *(const short8v*)&Alds[ar1*64 + (((ks*2 + hl) ^ (ar1 & 7))*8)];
        acc0 = __builtin_amdgcn_mfma_f32_32x32x16_bf16(a0, bf_, acc0, 0, 0, 0);
        acc1 = __builtin_amdgcn_mfma_f32_32x32x16_bf16(a1, bf_, acc1, 0, 0, 0);
      }
      __syncthreads();
    }
    #pragma unroll
    for (int r = 0; r < 16; ++r) {
      const int dl = (r & 3) + 8*(r >> 2) + 4*hl;
      const int d0 = mt*128 + mr*64 + dl;
      const size_t ob = ((size_t)(hh*DQ + d0))*DVD + nt*64 + nc*32 + l31;
      C_out[ob]            = acc0[r];
      C_out[ob + 32*DVD]   = acc1[r];
    }
  }
}

// ============================================================
// Attention main kernel — R10/R13 structure; ONE change: stageK(c+1)
// issued between sync1 and PV (Klds' last reader S(c) is done; the
// implicit vmcnt(0) at sync2 drains it, covered by PV). V/c staging
// unchanged (third sync). Dispatch order, swizzles, math bit-identical.
// ============================================================
__global__ __launch_bounds__(512, 2) void attn_kernel(
    const unsigned short* __restrict__ q_bf,
    const unsigned short* __restrict__ k_bf,
    const unsigned short* __restrict__ vt_bf,
    const float* __restrict__ ws,
    float* __restrict__ h_out) {
  const int b = blockIdx.x;
  const int phase = b >> 8;
  const int idx = b & 255;
  const int hh = idx & 15;
  const int vh = (idx >> 4) & 1;
  const int qq = idx >> 5;
  const int qi = phase ? (15 - qq) : qq;      // LPT: shorts first, longs desc
  const int nch = (qi >> 1) + 1;

  const int tid = threadIdx.x;
  const int w = tid >> 6, lane = tid & 63, l31 = lane & 31, hl = lane >> 5;
  const int tsub = w >> 2;        // 0..1: 32-row t-group
  const int sblk = w & 3;         // S-phase s-block
  const int vsub = w & 3;         // PV v-slice (64)

  __shared__ unsigned short Klds[128*256];   // 64 KB  [s][d], 32x16B slots/row
  __shared__ unsigned short Vtlds[256*128];  // 64 KB  [v][s], 16 slots/row
  __shared__ unsigned short Plds[64*128];    // 16 KB  [t][s], 16 slots/row
  __shared__ float c_lds[128];

  const float* a_g  = ws + WS_AT;
  const float* c_g  = ws + WS_CS;
  const float* hd_g = ws + WS_HDEN;

  const int tq = qi*64 + tsub*32 + l31;      // lane's t-column
  const float a_t = a_g[hh*SEQ + tq];

  short8v qfrag[16];
  #pragma unroll
  for (int d = 0; d < 16; ++d)
    qfrag[d] = *(const short8v*)(q_bf + ((size_t)(hh*SEQ + tq))*DQ + d*16 + hl*8);

  f32x16 acc0 = {}, acc1 = {};

  auto stageK = [&](int c) {
    const int s0 = c*128;
    #pragma unroll
    for (int p = 0; p < 8; ++p) {
      int u = p*512 + tid;
      int row = u >> 5, slot = u & 31;
      const unsigned short* src = k_bf +
          ((size_t)(hh*SEQ + s0 + row))*DQ + ((slot ^ (row & 31))*8);
      gl_lds16(src, (char*)Klds + (p*8 + w)*1024);
    }
  };
  auto stageV = [&](int c) {
    const int s0 = c*128;
    #pragma unroll
    for (int p = 0; p < 8; ++p) {
      int u = p*512 + tid;
      int row = u >> 4, slot = u & 15;
      const unsigned short* src = vt_bf +
          ((size_t)(hh*DVD + vh*256 + row))*SEQ + s0 + ((slot ^ (row & 15))*8);
      gl_lds16(src, (char*)Vtlds + (p*8 + w)*1024);
    }
    if (tid < 128) c_lds[tid] = c_g[hh*SEQ + s0 + tid];
  };

  stageK(0); stageV(0);
  __syncthreads();

  for (int c = 0; c < nch; ++c) {
    const int s0 = c*128;
    // ---- S-phase: S^T[s][t] for subtile (sblk, tsub) ----
    f32x16 sacc = {};
    const int srow = sblk*32 + l31;
    #pragma unroll
    for (int d = 0; d < 16; ++d) {
      short8v af = *(const short8v*)&Klds[srow*256 + (((d*2 + hl) ^ (srow & 31))*8)];
      sacc = __builtin_amdgcn_mfma_f32_32x32x16_bf16(af, qfrag[d], sacc, 0, 0, 0);
    }
    // weight, mask, pack bf16, write to Plds (swizzled)
    const int prow = tsub*32 + l31;
    #pragma unroll
    for (int i = 0; i < 8; ++i) {
      const int r0 = 2*i;
      const int sl = sblk*32 + (r0 & 3) + 8*(r0 >> 2) + 4*hl;
      const int sg = s0 + sl;
      const float c0 = c_lds[sl];
      const float c1 = c_lds[sl + 1];
      const float p0 = (sg     <= tq) ? __expf(a_t + c0) * sacc[r0]     : 0.f;
      const float p1 = (sg + 1 <= tq) ? __expf(a_t + c1) * sacc[r0 + 1] : 0.f;
      unsigned int pk;
      asm volatile("v_cvt_pk_bf16_f32 %0, %1, %2" : "=v"(pk) : "v"(p0), "v"(p1));
      const int byte = sl*2;
      const int slot = byte >> 4, rem = byte & 15;
      *(unsigned int*)((char*)Plds + prow*256 + ((slot ^ (prow & 15))<<4) + rem) = pk;
    }
    __syncthreads();   // sync1: P visible; Klds free (S done)

    // K(c+1) issued now — drains at sync2's implicit vmcnt(0), covered by PV
    if (c + 1 < nch) stageK(c + 1);

    // ---- PV phase: acc[t][v] += P[t][s] * V[s][v] ----
    #pragma unroll
    for (int ss = 0; ss < 8; ++ss) {
      const int arow = tsub*32 + l31;
      short8v pa = *(const short8v*)&Plds[arow*128 + (((ss*2 + hl) ^ (arow & 15))*8)];
      const int vr0 = vsub*64 + l31;
      const int slotB = (ss*2 + hl) ^ (l31 & 15);
      short8v vb0 = *(const short8v*)&Vtlds[vr0*128 + slotB*8];
      short8v vb1 = *(const short8v*)&Vtlds[(vr0 + 32)*128 + slotB*8];
      acc0 = __builtin_amdgcn_mfma_f32_32x32x16_bf16(pa, vb0, acc0, 0, 0, 0);
      acc1 = __builtin_amdgcn_mfma_f32_32x32x16_bf16(pa, vb1, acc1, 0, 0, 0);
    }
    __syncthreads();   // sync2: K(c+1) drained (covered by PV); Vtlds/Plds free

    if (c + 1 < nch) { stageV(c + 1); __syncthreads(); }  // V exposed (64 KB)
  }

  // ---- epilogue: exact denominator from ws, write h ----
  #pragma unroll
  for (int r = 0; r < 16; ++r) {
    const int tl = tsub*32 + (r & 3) + 8*(r >> 2) + 4*hl;
    const int tg = qi*64 + tl;
    const float inv = 1.0f / hd_g[hh*SEQ + tg];
    const size_t ob = ((size_t)(hh*SEQ + tg))*DVD + vh*256 + vsub*64 + l31;
    h_out[ob]      = acc0[r] * inv;
    h_out[ob + 32] = acc1[r] * inv;
  }
}

// ============================================================
extern "C" void kernel_launch(void* const* d_in, const int* in_sizes, int n_in,
                              void* d_out, int out_size, void* d_ws, size_t ws_size,
                              hipStream_t stream) {
  const float* q  = (const float*)d_in[0];
  const float* k  = (const float*)d_in[1];
  const float* v  = (const float*)d_in[2];
  const float* ip = (const float*)d_in[3];
  const float* fp = (const float*)d_in[4];

  float* h_out = (float*)d_out;                       // [16][1024][512]
  float* C_out = h_out + (size_t)NHH*SEQ*DVD;         // [16][256][512]
  float* n_out = C_out + (size_t)NHH*DQ*DVD;          // [16][256]
  float* m_out = n_out + NHH*DQ;                      // [16]
  float* ws    = (float*)d_ws;

  unsigned short* q_bf  = (unsigned short*)((char*)d_ws + QBF_OFF);
  unsigned short* k_bf  = (unsigned short*)((char*)d_ws + KBF_OFF);
  unsigned short* vt_bf = (unsigned short*)((char*)d_ws + VTB_OFF);
  unsigned short* kut   = (unsigned short*)((char*)d_ws + KUT_OFF);

  prep_kernel<<<768, 256, 0, stream>>>(k, v, ip, fp, ws, k_bf, vt_bf, kut, m_out);
  aux_kernel<<<512, 256, 0, stream>>>(k, q, ws, q_bf, n_out, kut, vt_bf, C_out);
  attn_kernel<<<512, 512, 0, stream>>>(q_bf, k_bf, vt_bf, ws, h_out);
}

// Round 16
// 84.756 us; speedup vs baseline: 1.4868x; 1.0435x over previous
//
#include <hip/hip_runtime.h>
#include <math.h>

#define SEQ   1024
#define DQ    256
#define DVD   512
#define NHH   16          // B*NH
#define EPSF  1e-6f
#define INV_SQRT_D 0.0625f   // 1/sqrt(256)

typedef __attribute__((ext_vector_type(8)))  short short8v;
typedef __attribute__((ext_vector_type(16))) float f32x16;

// ---- workspace layout (float offsets) ----
#define WS_FG    0                        // [16][1024]
#define WS_IG    (NHH*SEQ)                // [16][1024]
#define WS_ELIM  (2*NHH*SEQ)              // [16][1024]  exp(-m_t)
#define WS_HDEN  (3*NHH*SEQ)              // [16][1024]
#define WS_AT    (4*NHH*SEQ)              // [16][1024]  a_t = F_t - m_t
#define WS_CS    (5*NHH*SEQ)              // [16][1024]  c_s = i_s - F_s
#define WS_AC    (6*NHH*SEQ)              // [16][16]
#define WS_BVEC  (WS_AC + NHH*16)         // [16][16][256]
#define WS_SMALL_FLOATS (WS_BVEC + NHH*16*DQ)

#define QBF_OFF  ((size_t)WS_SMALL_FLOATS * 4)             // bytes (16-aligned)
#define KBF_OFF  (QBF_OFF + (size_t)NHH*SEQ*DQ*2)
#define VTB_OFF  (KBF_OFF + (size_t)NHH*SEQ*DQ*2)          // vt_bf [h][v][t]
#define KUT_OFF  (VTB_OFF + (size_t)NHH*DVD*SEQ*2)

__device__ __forceinline__ unsigned short f2bf(float f) {
  unsigned int u = __float_as_uint(f);
  return (unsigned short)((u + 0x7fffu + ((u >> 16) & 1u)) >> 16);
}

__device__ __forceinline__ void gl_lds16(const void* g, void* l) {
  __builtin_amdgcn_global_load_lds(
      (const __attribute__((address_space(1))) unsigned int*)g,
      (__attribute__((address_space(3))) unsigned int*)l, 16, 0, 0);
}

// ============================================================
// Role-fused prep kernel with INLINE gate scan (verbatim from R11/R13/R15).
// ============================================================
__global__ __launch_bounds__(256) void prep_kernel(
    const float* __restrict__ kin, const float* __restrict__ vin,
    const float* __restrict__ ipre, const float* __restrict__ fpre,
    float* __restrict__ ws,
    unsigned short* __restrict__ k_bf, unsigned short* __restrict__ vt_bf,
    unsigned short* __restrict__ kut, float* __restrict__ m_out) {
  __shared__ float lk[64][257];      // role-a k tile; role-b reuses as [32][33]
  __shared__ float swsum[4], swmax[4];
  __shared__ float bndF[16], bndM[16], fin2[2];
  __shared__ float cfg[64], cig[64], cut[64];

  const int b = blockIdx.x;
  if (b < 256) {
    const int hh = b >> 4, c = b & 15;
    const int d = threadIdx.x;
    const int lane = d & 63, wid = d >> 6;   // 4 waves
    const int tbase = hh*SEQ + c*64;
    const size_t base = (size_t)tbase * DQ;

    #pragma unroll 4
    for (int tt = 0; tt < 64; ++tt) {
      const float val = kin[base + (size_t)tt*DQ + d];
      lk[tt][d] = val;
      k_bf[base + (size_t)tt*DQ + d] = f2bf(val);
    }

    const float4 f4 = *(const float4*)(fpre + hh*SEQ + 4*d);
    const float4 i4 = *(const float4*)(ipre + hh*SEQ + 4*d);
    float fv[4] = {f4.x, f4.y, f4.z, f4.w};
    float iv[4] = {i4.x, i4.y, i4.z, i4.w};
    float fl[4], F[4];
    float s = 0.f;
    #pragma unroll
    for (int j = 0; j < 4; ++j) {
      fl[j] = fminf(fv[j], 0.f) - log1pf(expf(-fabsf(fv[j])));
      s += fl[j]; F[j] = s;
    }
    float wsc = s;
    #pragma unroll
    for (int off = 1; off < 64; off <<= 1) {
      float o = __shfl_up(wsc, off, 64);
      if (lane >= off) wsc += o;
    }
    if (lane == 63) swsum[wid] = wsc;
    __syncthreads();
    float woff = 0.f;
    #pragma unroll
    for (int i = 0; i < 4; ++i) { float t = swsum[i]; if (i < wid) woff += t; }
    const float Fexc = woff + (wsc - s);
    #pragma unroll
    for (int j = 0; j < 4; ++j) F[j] += Fexc;

    float zser[4];
    float zs = -INFINITY;
    #pragma unroll
    for (int j = 0; j < 4; ++j) {
      zs = fmaxf(zs, iv[j] - F[j]); zser[j] = zs;
    }
    float zmI = zs;
    #pragma unroll
    for (int off = 1; off < 64; off <<= 1) {
      float o = __shfl_up(zmI, off, 64);
      if (lane >= off) zmI = fmaxf(zmI, o);
    }
    if (lane == 63) swmax[wid] = zmI;
    float zexcl = __shfl_up(zmI, 1, 64);
    if (lane == 0) zexcl = -INFINITY;
    __syncthreads();
    float zoffW = -INFINITY;
    #pragma unroll
    for (int i = 0; i < 4; ++i) { float t = swmax[i]; if (i < wid) zoffW = fmaxf(zoffW, t); }
    const float zPexc = fmaxf(zoffW, zexcl);

    float mprev = Fexc + fmaxf(zPexc, 0.f);
    float m_[4], fg_[4], ig_[4];
    #pragma unroll
    for (int j = 0; j < 4; ++j) {
      const float zP = fmaxf(zPexc, zser[j]);
      m_[j] = F[j] + fmaxf(zP, 0.f);
      fg_[j] = expf(fl[j] + mprev - m_[j]);
      ig_[j] = expf(iv[j] - m_[j]);
      mprev = m_[j];
    }

    if ((d & 15) == 15) { bndF[d >> 4] = F[3]; bndM[d >> 4] = m_[3]; }
    if (d == 255)       { fin2[0] = F[3]; fin2[1] = m_[3]; }
    const int q0 = d - 16*c;
    if (q0 >= 0 && q0 < 16) {
      #pragma unroll
      for (int j = 0; j < 4; ++j) { cfg[q0*4 + j] = fg_[j]; cig[q0*4 + j] = ig_[j]; }
    }
    if (c == 0) {
      float4 o;
      o.x=fg_[0]; o.y=fg_[1]; o.z=fg_[2]; o.w=fg_[3];
      *(float4*)(ws + WS_FG + hh*SEQ + 4*d) = o;
      o.x=ig_[0]; o.y=ig_[1]; o.z=ig_[2]; o.w=ig_[3];
      *(float4*)(ws + WS_IG + hh*SEQ + 4*d) = o;
      o.x=expf(-m_[0]); o.y=expf(-m_[1]); o.z=expf(-m_[2]); o.w=expf(-m_[3]);
      *(float4*)(ws + WS_ELIM + hh*SEQ + 4*d) = o;
      o.x=F[0]-m_[0]; o.y=F[1]-m_[1]; o.z=F[2]-m_[2]; o.w=F[3]-m_[3];
      *(float4*)(ws + WS_AT + hh*SEQ + 4*d) = o;
      o.x=iv[0]-F[0]; o.y=iv[1]-F[1]; o.z=iv[2]-F[2]; o.w=iv[3]-F[3];
      *(float4*)(ws + WS_CS + hh*SEQ + 4*d) = o;
      if (d == 255) m_out[hh] = m_[3];
    }
    __syncthreads();
    if (c == 0 && d < 16) {
      const float Fp = d ? bndF[d-1] : 0.f;
      const float mp = d ? bndM[d-1] : 0.f;
      ws[WS_AC + hh*16 + d] = expf((bndF[d] - Fp) + (mp - bndM[d]));
    }
    if (q0 >= 0 && q0 < 16) {
      const float Fe = fin2[0], me = fin2[1];
      #pragma unroll
      for (int j = 0; j < 4; ++j)
        cut[q0*4 + j] = expf(Fe - F[j] + iv[j] - me);
    }
    __syncthreads();

    float nb = 0.f;
    #pragma unroll 8
    for (int tt = 0; tt < 64; ++tt) nb = cfg[tt]*nb + cig[tt]*lk[tt][d];
    ws[WS_BVEC + (hh*16 + c)*DQ + d] = nb;
    #pragma unroll
    for (int g = 0; g < 8; ++g) {
      short8v pk;
      #pragma unroll
      for (int j = 0; j < 8; ++j) {
        const int tt = g*8 + j;
        pk[j] = (short)f2bf(cut[tt] * lk[tt][d]);
      }
      *(short8v*)(kut + ((size_t)(hh*DQ + d))*SEQ + c*64 + g*8) = pk;
    }
  } else {
    const int b2 = b - 256;            // 0..511
    const int hh = b2 >> 5, tg = b2 & 31;
    const int tx = threadIdx.x & 31, ty = threadIdx.x >> 5;
    float (*tile)[33] = (float(*)[33])lk;
    for (int vt = 0; vt < 16; ++vt) {
      #pragma unroll
      for (int i = 0; i < 4; ++i)
        tile[ty + 8*i][tx] =
            vin[((size_t)(hh*SEQ + tg*32 + ty + 8*i))*DVD + vt*32 + tx];
      __syncthreads();
      #pragma unroll
      for (int i = 0; i < 4; ++i)
        vt_bf[((size_t)(hh*DVD + vt*32 + ty + 8*i))*SEQ + tg*32 + tx] =
            f2bf(tile[tx][ty + 8*i]);
      __syncthreads();
    }
  }
}

// ============================================================
// Merged aux kernel (verbatim R13/R15): hden (blocks 0..255) + cgemm
// (blocks 256..511). Union'd LDS (66.5 KB -> 2 blocks/CU).
// ============================================================
__global__ __launch_bounds__(256) void aux_kernel(
    const float* __restrict__ kin, const float* __restrict__ qin,
    float* __restrict__ ws, unsigned short* __restrict__ q_bf,
    float* __restrict__ n_out,
    const unsigned short* __restrict__ kut,
    const unsigned short* __restrict__ vt,
    float* __restrict__ C_out) {
  __shared__ __align__(16) char smem[66560];
  const int b = blockIdx.x;

  if (b < 256) {
    // ---------------- hden role ----------------
    float (*pbuf)[DQ] = (float(*)[DQ])smem;            // 64 KB
    float (*spart)[4] = (float(*)[4])(smem + 65536);   //  1 KB
    const int hh = b >> 4;
    const int c  = b & 15;
    const int d  = threadIdx.x;

    float n = 0.f;
    for (int j = 0; j < c; ++j)
      n = ws[WS_AC + hh*16 + j]*n + ws[WS_BVEC + (hh*16 + j)*DQ + d];
    if (c == 15) {
      const float nf = ws[WS_AC + hh*16 + 15]*n +
                       ws[WS_BVEC + (hh*16 + 15)*DQ + d];
      n_out[hh*DQ + d] = nf;
    }

    const int tbase = hh*SEQ + c*64;
    const size_t base = (size_t)tbase * DQ;
    #pragma unroll 4
    for (int tt = 0; tt < 64; ++tt) {
      const float fg = ws[WS_FG + tbase + tt];
      const float ig = ws[WS_IG + tbase + tt];
      n = fg*n + ig*kin[base + (size_t)tt*DQ + d];
      const float qv = qin[base + (size_t)tt*DQ + d];
      q_bf[base + (size_t)tt*DQ + d] = f2bf(qv * INV_SQRT_D);
      pbuf[tt][d] = n * qv;
    }
    __syncthreads();

    {
      const int tt = d >> 2, qd = d & 3;
      float s = 0.f;
      #pragma unroll 8
      for (int j = 0; j < 64; ++j)
        s += pbuf[tt][qd*64 + ((j + d) & 63)];
      spart[tt][qd] = s;
    }
    __syncthreads();
    if (d < 64) {
      const float tot = (spart[d][0] + spart[d][1]) + (spart[d][2] + spart[d][3]);
      const float qn = tot * INV_SQRT_D;
      const float hd = fmaxf(fabsf(qn), ws[WS_ELIM + tbase + d]) + EPSF;
      ws[WS_HDEN + tbase + d] = hd;
    }
  } else {
    // ---------------- cgemm role ----------------
    unsigned short* Alds = (unsigned short*)smem;            // 16 KB [d][t]
    unsigned short* Blds = (unsigned short*)(smem + 16384);  //  8 KB [v][t]
    const int b2 = b - 256;       // 16h x 2mt x 8nt
    const int hh = b2 >> 4;
    const int mt = (b2 >> 3) & 1;
    const int nt = b2 & 7;
    const int tid = threadIdx.x;
    const int w = tid >> 6, lane = tid & 63, l31 = lane & 31, hl = lane >> 5;
    const int mr = w >> 1;
    const int nc = w & 1;

    f32x16 acc0 = {}, acc1 = {};
    for (int c = 0; c < 16; ++c) {
      const int t0 = c*64;
      #pragma unroll
      for (int p = 0; p < 4; ++p) {
        int u = p*256 + tid; int row = u >> 3, slot = u & 7;
        const unsigned short* src = kut +
            ((size_t)(hh*DQ + mt*128 + row))*SEQ + t0 + ((slot ^ (row & 7))*8);
        gl_lds16(src, (char*)Alds + (p*4 + w)*1024);
      }
      #pragma unroll
      for (int p = 0; p < 2; ++p) {
        int u = p*256 + tid; int row = u >> 3, slot = u & 7;
        const unsigned short* src = vt +
            ((size_t)(hh*DVD + nt*64 + row))*SEQ + t0 + ((slot ^ (row & 7))*8);
        gl_lds16(src, (char*)Blds + (p*4 + w)*1024);
      }
      __syncthreads();
      #pragma unroll
      for (int ks = 0; ks < 4; ++ks) {
        const int br = nc*32 + l31;
        short8v bf_ = *(const short8v*)&Blds[br*64 + (((ks*2 + hl) ^ (br & 7))*8)];
        const int ar0 = mr*64 + l31, ar1 = ar0 + 32;
        short8v a0 = *(const short8v*)&Alds[ar0*64 + (((ks*2 + hl) ^ (ar0 & 7))*8)];
        short8v a1 = *(const short8v*)&Alds[ar1*64 + (((ks*2 + hl) ^ (ar1 & 7))*8)];
        acc0 = __builtin_amdgcn_mfma_f32_32x32x16_bf16(a0, bf_, acc0, 0, 0, 0);
        acc1 = __builtin_amdgcn_mfma_f32_32x32x16_bf16(a1, bf_, acc1, 0, 0, 0);
      }
      __syncthreads();
    }
    #pragma unroll
    for (int r = 0; r < 16; ++r) {
      const int dl = (r & 3) + 8*(r >> 2) + 4*hl;
      const int d0 = mt*128 + mr*64 + dl;
      const size_t ob = ((size_t)(hh*DQ + d0))*DVD + nt*64 + nc*32 + l31;
      C_out[ob]            = acc0[r];
      C_out[ob + 32*DVD]   = acc1[r];
    }
  }
}

// ============================================================
// Attention main kernel — R10 structure; 2 barriers/chunk.
//  sync1: pure barrier (no outstanding vmem) — orders Plds + frees Klds.
//  stageK(c+1) after sync1, drains at sync2 under PV cover.
//  stageV(c+1) after sync2, drains before pack(c+1) (cv-load wait) under
//  S(c+1) cover.  c-values prefetched to registers per chunk (replaces
//  c_lds — removing the 3rd barrier made LDS-staged c a race).
// All math/swizzles/dispatch bit-identical to the 45 us kernel.
// ============================================================
__global__ __launch_bounds__(512, 2) void attn_kernel(
    const unsigned short* __restrict__ q_bf,
    const unsigned short* __restrict__ k_bf,
    const unsigned short* __restrict__ vt_bf,
    const float* __restrict__ ws,
    float* __restrict__ h_out) {
  const int b = blockIdx.x;
  const int phase = b >> 8;
  const int idx = b & 255;
  const int hh = idx & 15;
  const int vh = (idx >> 4) & 1;
  const int qq = idx >> 5;
  const int qi = phase ? (15 - qq) : qq;      // LPT: shorts first, longs desc
  const int nch = (qi >> 1) + 1;

  const int tid = threadIdx.x;
  const int w = tid >> 6, lane = tid & 63, l31 = lane & 31, hl = lane >> 5;
  const int tsub = w >> 2;        // 0..1: 32-row t-group
  const int sblk = w & 3;         // S-phase s-block
  const int vsub = w & 3;         // PV v-slice (64)

  __shared__ unsigned short Klds[128*256];   // 64 KB  [s][d], 32x16B slots/row
  __shared__ unsigned short Vtlds[256*128];  // 64 KB  [v][s], 16 slots/row
  __shared__ unsigned short Plds[64*128];    // 16 KB  [t][s], 16 slots/row

  const float* a_g  = ws + WS_AT;
  const float* c_g  = ws + WS_CS + hh*SEQ;
  const float* hd_g = ws + WS_HDEN;

  const int tq = qi*64 + tsub*32 + l31;      // lane's t-column
  const float a_t = a_g[hh*SEQ + tq];

  short8v qfrag[16];
  #pragma unroll
  for (int d = 0; d < 16; ++d)
    qfrag[d] = *(const short8v*)(q_bf + ((size_t)(hh*SEQ + tq))*DQ + d*16 + hl*8);

  f32x16 acc0 = {}, acc1 = {};

  auto stageK = [&](int c) {
    const int s0 = c*128;
    #pragma unroll
    for (int p = 0; p < 8; ++p) {
      int u = p*512 + tid;
      int row = u >> 5, slot = u & 31;
      const unsigned short* src = k_bf +
          ((size_t)(hh*SEQ + s0 + row))*DQ + ((slot ^ (row & 31))*8);
      gl_lds16(src, (char*)Klds + (p*8 + w)*1024);
    }
  };
  auto stageV = [&](int c) {
    const int s0 = c*128;
    #pragma unroll
    for (int p = 0; p < 8; ++p) {
      int u = p*512 + tid;
      int row = u >> 4, slot = u & 15;
      const unsigned short* src = vt_bf +
          ((size_t)(hh*DVD + vh*256 + row))*SEQ + s0 + ((slot ^ (row & 15))*8);
      gl_lds16(src, (char*)Vtlds + (p*8 + w)*1024);
    }
  };

  stageK(0); stageV(0);
  __syncthreads();

  for (int c = 0; c < nch; ++c) {
    const int s0 = c*128;

    // ---- c-value register prefetch (covers stageV(c)'s residual drain) ----
    float cvx[8], cvy[8];
    #pragma unroll
    for (int i = 0; i < 8; ++i) {
      const int r0 = 2*i;
      const int sl = sblk*32 + (r0 & 3) + 8*(r0 >> 2) + 4*hl;
      const float2 cc = *(const float2*)(c_g + s0 + sl);
      cvx[i] = cc.x; cvy[i] = cc.y;
    }

    // ---- S-phase: S^T[s][t] for subtile (sblk, tsub) ----
    f32x16 sacc = {};
    const int srow = sblk*32 + l31;
    #pragma unroll
    for (int d = 0; d < 16; ++d) {
      short8v af = *(const short8v*)&Klds[srow*256 + (((d*2 + hl) ^ (srow & 31))*8)];
      sacc = __builtin_amdgcn_mfma_f32_32x32x16_bf16(af, qfrag[d], sacc, 0, 0, 0);
    }
    // ---- weight, mask, pack bf16, write to Plds (swizzled) ----
    const int prow = tsub*32 + l31;
    #pragma unroll
    for (int i = 0; i < 8; ++i) {
      const int r0 = 2*i;
      const int sl = sblk*32 + (r0 & 3) + 8*(r0 >> 2) + 4*hl;
      const int sg = s0 + sl;
      const float p0 = (sg     <= tq) ? __expf(a_t + cvx[i]) * sacc[r0]     : 0.f;
      const float p1 = (sg + 1 <= tq) ? __expf(a_t + cvy[i]) * sacc[r0 + 1] : 0.f;
      unsigned int pk;
      asm volatile("v_cvt_pk_bf16_f32 %0, %1, %2" : "=v"(pk) : "v"(p0), "v"(p1));
      const int byte = sl*2;
      const int slot = byte >> 4, rem = byte & 15;
      *(unsigned int*)((char*)Plds + prow*256 + ((slot ^ (prow & 15))<<4) + rem) = pk;
    }
    __syncthreads();   // sync1: pure barrier — P visible; Klds free (S done)

    // K(c+1) issued now — drains at sync2's implicit vmcnt(0), covered by PV
    if (c + 1 < nch) stageK(c + 1);

    // ---- PV phase: acc[t][v] += P[t][s] * V[s][v] ----
    #pragma unroll
    for (int ss = 0; ss < 8; ++ss) {
      const int arow = tsub*32 + l31;
      short8v pa = *(const short8v*)&Plds[arow*128 + (((ss*2 + hl) ^ (arow & 15))*8)];
      const int vr0 = vsub*64 + l31;
      const int slotB = (ss*2 + hl) ^ (l31 & 15);
      short8v vb0 = *(const short8v*)&Vtlds[vr0*128 + slotB*8];
      short8v vb1 = *(const short8v*)&Vtlds[(vr0 + 32)*128 + slotB*8];
      acc0 = __builtin_amdgcn_mfma_f32_32x32x16_bf16(pa, vb0, acc0, 0, 0, 0);
      acc1 = __builtin_amdgcn_mfma_f32_32x32x16_bf16(pa, vb1, acc1, 0, 0, 0);
    }
    __syncthreads();   // sync2: K(c+1) drained (PV-covered); Vtlds/Plds free

    // V(c+1) issued now — drains before pack(c+1), covered by S(c+1)
    if (c + 1 < nch) stageV(c + 1);
  }

  // ---- epilogue: exact denominator from ws, write h ----
  #pragma unroll
  for (int r = 0; r < 16; ++r) {
    const int tl = tsub*32 + (r & 3) + 8*(r >> 2) + 4*hl;
    const int tg = qi*64 + tl;
    const float inv = 1.0f / hd_g[hh*SEQ + tg];
    const size_t ob = ((size_t)(hh*SEQ + tg))*DVD + vh*256 + vsub*64 + l31;
    h_out[ob]      = acc0[r] * inv;
    h_out[ob + 32] = acc1[r] * inv;
  }
}

// ============================================================
extern "C" void kernel_launch(void* const* d_in, const int* in_sizes, int n_in,
                              void* d_out, int out_size, void* d_ws, size_t ws_size,
                              hipStream_t stream) {
  const float* q  = (const float*)d_in[0];
  const float* k  = (const float*)d_in[1];
  const float* v  = (const float*)d_in[2];
  const float* ip = (const float*)d_in[3];
  const float* fp = (const float*)d_in[4];

  float* h_out = (float*)d_out;                       // [16][1024][512]
  float* C_out = h_out + (size_t)NHH*SEQ*DVD;         // [16][256][512]
  float* n_out = C_out + (size_t)NHH*DQ*DVD;          // [16][256]
  float* m_out = n_out + NHH*DQ;                      // [16]
  float* ws    = (float*)d_ws;

  unsigned short* q_bf  = (unsigned short*)((char*)d_ws + QBF_OFF);
  unsigned short* k_bf  = (unsigned short*)((char*)d_ws + KBF_OFF);
  unsigned short* vt_bf = (unsigned short*)((char*)d_ws + VTB_OFF);
  unsigned short* kut   = (unsigned short*)((char*)d_ws + KUT_OFF);

  prep_kernel<<<768, 256, 0, stream>>>(k, v, ip, fp, ws, k_bf, vt_bf, kut, m_out);
  aux_kernel<<<512, 256, 0, stream>>>(k, q, ws, q_bf, n_out, kut, vt_bf, C_out);
  attn_kernel<<<512, 512, 0, stream>>>(q_bf, k_bf, vt_bf, ws, h_out);
}